// Round 1
// 4309.609 us; speedup vs baseline: 1.1968x; 1.1968x over previous
//
#include <hip/hip_runtime.h>

#define USH unsigned short

// ---------- bf16 helpers (bit-exact, no __bf16 arithmetic) ----------
__device__ __forceinline__ float bf2f(USH u) {
    return __uint_as_float(((unsigned int)u) << 16);
}
__device__ __forceinline__ float bfbits2f(unsigned int b) {
    return __uint_as_float(b << 16);
}
__device__ __forceinline__ USH f2bf(float f) {
    unsigned int x = __float_as_uint(f);
    x += 0x7fffu + ((x >> 16) & 1u);   // RNE
    return (USH)(x >> 16);
}
__device__ __forceinline__ unsigned int pack2bf(float a, float b) {
    return (unsigned int)f2bf(a) | ((unsigned int)f2bf(b) << 16);
}
__device__ __forceinline__ float sigmoidf_(float x) { return 1.0f / (1.0f + expf(-x)); }

typedef __bf16 bf16x8 __attribute__((ext_vector_type(8)));
typedef float floatx4 __attribute__((ext_vector_type(4)));

// async global->LDS, 16B per lane, wave-uniform LDS base (dest = base + lane*16)
#define GLOAD_LDS16(g, l) __builtin_amdgcn_global_load_lds( \
    (const __attribute__((address_space(1))) void*)(g),     \
    (__attribute__((address_space(3))) void*)(l), 16, 0, 0)

// ---------------------------------------------------------------
// BT-GEMM: C[m,n] = epi( sum_k A[m,k] * W[n,k] + bias[n] )
// m97 structure: 128x128 tile, BK=32, linear LDS [128][32] (64B rows),
// global_load_lds width=16 staging, 4 waves (2x2 of 64x64), 16x16x32 MFMA.
// A-frag: lane holds A[m=lane&15][k=(lane>>4)*8+j]; W-frag same with n.
// C/D: col=lane&15, row=(lane>>4)*4+reg   [measured m89/m91]
// WF32=true keeps the old reg-staging for W (fp32 -> bf16 pack) — used only
// for the two tiny M=128 GEMMs where a separate conversion pass doesn't pay.
// ---------------------------------------------------------------
enum { EPI_SCORES = 0, EPI_GELU = 1, EPI_GATE = 2, EPI_PLAIN = 3 };

template <int EPI, bool WF32>
__global__ __launch_bounds__(256)
void gemm_bt(const USH* __restrict__ A, int lda, long long sAz,
             const void* __restrict__ Wv, int ldw, long long sWz,
             void* __restrict__ Cout, int ldc, long long sCz,
             const float* __restrict__ bias, const float* __restrict__ fmul,
             float alpha, int Kd)
{
    __shared__ USH As[128 * 32];    // 8 KB, linear: row stride 32 bf16 = 64 B
    __shared__ USH Ws[128 * 32];    // 8 KB
    const int z = blockIdx.z;
    A += (size_t)z * (size_t)sAz;
    const USH* Wb = (const USH*)Wv + (size_t)z * (size_t)sWz;
    const float* Wf = (const float*)Wv;
    const int m0 = blockIdx.y * 128;
    const int n0 = blockIdx.x * 128;
    const int tid = threadIdx.x;
    const int lane = tid & 63;
    const int wid = tid >> 6;
    const int wm = (wid >> 1) * 64;
    const int wn = (wid & 1) * 64;
    const int q = lane >> 4;
    const int r = lane & 15;

    floatx4 acc[4][4] = {};

    // --- global_load_lds staging geometry ---
    // chunk c = wid*2 + i covers rows [c*16, c*16+16); each issue = 1024 B.
    // lane l -> row c*16 + (l>>2), col (l&3)*8 bf16  (matches linear LDS)
    const int c0 = wid * 2;
    const int grow = c0 * 16 + (lane >> 2);
    const int gcol = (lane & 3) * 8;
    const USH* apA0 = A + (size_t)(m0 + grow) * lda + gcol;
    const USH* apA1 = apA0 + (size_t)16 * lda;
    USH* lA0 = &As[c0 * 512];
    USH* lA1 = &As[(c0 + 1) * 512];
    const USH* apW0 = Wb + (size_t)(n0 + grow) * ldw + gcol;
    const USH* apW1 = apW0 + (size_t)16 * ldw;
    USH* lW0 = &Ws[c0 * 512];
    USH* lW1 = &Ws[(c0 + 1) * 512];

    // --- WF32 reg-staging geometry (W only) ---
    const int frow = tid >> 1;
    const int fcol = (tid & 1) * 16;
    const float* wpf = Wf + (size_t)(n0 + frow) * ldw + fcol;
    USH* wsw = &Ws[frow * 32 + fcol];

    for (int k0 = 0; k0 < Kd; k0 += 32) {
        GLOAD_LDS16(apA0 + k0, lA0);
        GLOAD_LDS16(apA1 + k0, lA1);
        if (WF32) {
            float4 f0 = *reinterpret_cast<const float4*>(wpf + k0);
            float4 f1 = *reinterpret_cast<const float4*>(wpf + k0 + 4);
            float4 f2 = *reinterpret_cast<const float4*>(wpf + k0 + 8);
            float4 f3 = *reinterpret_cast<const float4*>(wpf + k0 + 12);
            uint4 w0, w1;
            w0.x = pack2bf(f0.x, f0.y); w0.y = pack2bf(f0.z, f0.w);
            w0.z = pack2bf(f1.x, f1.y); w0.w = pack2bf(f1.z, f1.w);
            w1.x = pack2bf(f2.x, f2.y); w1.y = pack2bf(f2.z, f2.w);
            w1.z = pack2bf(f3.x, f3.y); w1.w = pack2bf(f3.z, f3.w);
            *reinterpret_cast<uint4*>(wsw) = w0;
            *reinterpret_cast<uint4*>(wsw + 8) = w1;
        } else {
            GLOAD_LDS16(apW0 + k0, lW0);
            GLOAD_LDS16(apW1 + k0, lW1);
        }
        __syncthreads();
        bf16x8 af[4], wf4[4];
#pragma unroll
        for (int i = 0; i < 4; i++)
            af[i] = *reinterpret_cast<const bf16x8*>(&As[(wm + i * 16 + r) * 32 + q * 8]);
#pragma unroll
        for (int j = 0; j < 4; j++)
            wf4[j] = *reinterpret_cast<const bf16x8*>(&Ws[(wn + j * 16 + r) * 32 + q * 8]);
#pragma unroll
        for (int i = 0; i < 4; i++)
#pragma unroll
            for (int j = 0; j < 4; j++)
                acc[i][j] = __builtin_amdgcn_mfma_f32_16x16x32_bf16(af[i], wf4[j], acc[i][j], 0, 0, 0);
        __syncthreads();
    }

#pragma unroll
    for (int j = 0; j < 4; j++) {
        const int col = n0 + wn + j * 16 + r;
        const float bv = (EPI == EPI_SCORES) ? 0.f : bias[col];
#pragma unroll
        for (int i = 0; i < 4; i++) {
            const int row0 = m0 + wm + i * 16 + q * 4;
#pragma unroll
            for (int rr = 0; rr < 4; rr++) {
                const int row = row0 + rr;
                float v = acc[i][j][rr];
                if (EPI == EPI_SCORES) {
                    ((float*)Cout)[(size_t)z * (size_t)sCz + (size_t)row * ldc + col] = v * alpha;
                } else if (EPI == EPI_GELU) {
                    v += bv;
                    float g = 0.5f * v * (1.0f + erff(v * 0.7071067811865475f));
                    ((USH*)Cout)[(size_t)row * ldc + col] = f2bf(g);
                } else if (EPI == EPI_GATE) {
                    v += bv;
                    float gate = 1.0f / (1.0f + expf(-v));
                    float o = gate * fmul[(size_t)row * ldc + col];
                    ((USH*)Cout)[(size_t)row * ldc + col] = f2bf(o);
                } else {
                    ((USH*)Cout)[(size_t)row * ldc + col] = f2bf(v + bv);
                }
            }
        }
    }
}

// ---------------------------------------------------------------
// means: z<24 -> y[z][d] = mean_n feats[z,n,d]; z==24 -> tg[d] = mean_t text
// z==25 -> init cell state (c=0, sigmoid(c)=0.5)
// ---------------------------------------------------------------
__global__ __launch_bounds__(256)
void means_k(const float* __restrict__ text, const float* __restrict__ feats,
             float* __restrict__ tg, float* __restrict__ yv, float* __restrict__ cst,
             float* __restrict__ scs)
{
    const int d = blockIdx.x * 256 + threadIdx.x;
    const int z = blockIdx.y;
    if (z < 24) {
        const float* f = feats + (size_t)z * 576 * 4096 + d;
        float s = 0.f;
        for (int n = 0; n < 576; n++) s += f[(size_t)n * 4096];
        yv[z * 4096 + d] = s * (1.0f / 576.0f);
    } else if (z == 24) {
        float s = 0.f;
        for (int t = 0; t < 128; t++) s += text[(size_t)t * 4096 + d];
        tg[d] = s * (1.0f / 128.0f);
    } else {
        cst[d] = 0.f;
        scs[d] = 0.5f;
    }
}

// ---------------------------------------------------------------
// f32 -> bf16 bulk convert (text, and the 3 big weight matrices)
// ---------------------------------------------------------------
__global__ __launch_bounds__(256)
void f32_to_bf16(const float* __restrict__ src, USH* __restrict__ dst)
{
    const size_t base = ((size_t)blockIdx.x * 256 + threadIdx.x) * 8;
    float4 f0 = *reinterpret_cast<const float4*>(src + base);
    float4 f1 = *reinterpret_cast<const float4*>(src + base + 4);
    uint4 ov;
    ov.x = pack2bf(f0.x, f0.y); ov.y = pack2bf(f0.z, f0.w);
    ov.z = pack2bf(f1.x, f1.y); ov.w = pack2bf(f1.z, f1.w);
    *reinterpret_cast<uint4*>(dst + base) = ov;
}

// ---------------------------------------------------------------
// DSU precompute (recurrence-independent 2/3 of W1 matvec):
// pre[l,r] = W1[r,4096:8192].y_l + W1[r,8192:12288].tg + W1_b[r]
// one block per r; weight row cached in registers across the 24 layers.
// ---------------------------------------------------------------
__global__ __launch_bounds__(256)
void dsu_pre(const float* __restrict__ W1w, const float* __restrict__ W1b,
             const float* __restrict__ yv, const float* __restrict__ tg,
             float* __restrict__ pre)
{
    const int rrow = blockIdx.x;
    const float* w = W1w + (size_t)rrow * 12288;
    const int tid = threadIdx.x;
    float wy[16];
    float at = 0.f;
#pragma unroll
    for (int i = 0; i < 16; i++) {
        const int k = tid + i * 256;
        wy[i] = w[4096 + k];
        at += w[8192 + k] * tg[k];
    }
#pragma unroll
    for (int o = 32; o > 0; o >>= 1) at += __shfl_down(at, o, 64);
    __shared__ float red[4];
    __shared__ float tgs;
    if ((tid & 63) == 0) red[tid >> 6] = at;
    __syncthreads();
    if (tid == 0) tgs = red[0] + red[1] + red[2] + red[3] + W1b[rrow];
    for (int l = 0; l < 24; l++) {
        const float* y = yv + (size_t)l * 4096;
        float a = 0.f;
#pragma unroll
        for (int i = 0; i < 16; i++) a += wy[i] * y[tid + i * 256];
#pragma unroll
        for (int o = 32; o > 0; o >>= 1) a += __shfl_down(a, o, 64);
        __syncthreads();           // protect red (and l==0: tgs read order for tid0 only)
        if ((tid & 63) == 0) red[tid >> 6] = a;
        __syncthreads();
        if (tid == 0) pre[l * 1024 + rrow] = red[0] + red[1] + red[2] + red[3] + tgs;
    }
}

// ---------------------------------------------------------------
// DSU step 1 (sequential part only): s[r] = relu(W1[r,0:4096].sig(c) + pre[l,r])
// ---------------------------------------------------------------
__global__ __launch_bounds__(256)
void dsu_s1(const float* __restrict__ W1w, const float* __restrict__ scs,
            const float* __restrict__ pre_l, float* __restrict__ sv)
{
    const int rrow = blockIdx.x;
    const float* w = W1w + (size_t)rrow * 12288;
    const int tid = threadIdx.x;
    float acc = 0.f;
#pragma unroll
    for (int i = 0; i < 16; i++) {
        const int k = tid + i * 256;
        acc += w[k] * scs[k];
    }
#pragma unroll
    for (int o = 32; o > 0; o >>= 1) acc += __shfl_down(acc, o, 64);
    __shared__ float red[4];
    if ((tid & 63) == 0) red[tid >> 6] = acc;
    __syncthreads();
    if (tid == 0) {
        float t = red[0] + red[1] + red[2] + red[3] + pre_l[rrow];
        sv[rrow] = fmaxf(t, 0.f);
    }
}

// ---------------------------------------------------------------
// DSU step 2: gates + cell update + ctx write + cached sigmoid(c)
// ---------------------------------------------------------------
__global__ __launch_bounds__(256)
void dsu_s2(const float* __restrict__ Wc, const float* __restrict__ Wcb,
            const float* __restrict__ Wi, const float* __restrict__ Wib,
            const float* __restrict__ Wf, const float* __restrict__ Wfb,
            const float* __restrict__ bc, const float* __restrict__ bi,
            const float* __restrict__ bfv,
            const float* __restrict__ sv, float* __restrict__ c,
            float* __restrict__ ctx_l, float* __restrict__ scs)
{
    const int d = blockIdx.x;
    const int tid = threadIdx.x;
    float a0 = 0.f, a1 = 0.f, a2 = 0.f;
    for (int k = tid; k < 1024; k += 256) {
        float s = sv[k];
        a0 += Wc[(size_t)d * 1024 + k] * s;
        a1 += Wi[(size_t)d * 1024 + k] * s;
        a2 += Wf[(size_t)d * 1024 + k] * s;
    }
#pragma unroll
    for (int o = 32; o > 0; o >>= 1) {
        a0 += __shfl_down(a0, o, 64);
        a1 += __shfl_down(a1, o, 64);
        a2 += __shfl_down(a2, o, 64);
    }
    __shared__ float red[3][4];
    if ((tid & 63) == 0) {
        red[0][tid >> 6] = a0; red[1][tid >> 6] = a1; red[2][tid >> 6] = a2;
    }
    __syncthreads();
    if (tid == 0) {
        float A0 = red[0][0] + red[0][1] + red[0][2] + red[0][3];
        float A1 = red[1][0] + red[1][1] + red[1][2] + red[1][3];
        float A2 = red[2][0] + red[2][1] + red[2][2] + red[2][3];
        float ct = tanhf(A0 + Wcb[d] + bc[d]);
        float ig = sigmoidf_(A1 + Wib[d] + bi[d]);
        float fg = sigmoidf_(A2 + Wfb[d] + bfv[d]);
        float cn = fg * c[d] + ig * ct;
        c[d] = cn;
        ctx_l[d] = cn;
        scs[d] = sigmoidf_(cn);
    }
}

// ---------------------------------------------------------------
// X = bf16( feats + ctx[layer] )   (8 elements/thread); feats fp32
// ---------------------------------------------------------------
__global__ __launch_bounds__(256)
void make_x(const float* __restrict__ feats, const float* __restrict__ ctx,
            USH* __restrict__ X)
{
    const size_t base = ((size_t)blockIdx.x * 256 + threadIdx.x) * 8;
    const int row = (int)(base >> 12);
    const int l = row / 576;
    const float* cr = ctx + (size_t)l * 4096 + (base & 4095);
    float4 f0 = *reinterpret_cast<const float4*>(feats + base);
    float4 f1 = *reinterpret_cast<const float4*>(feats + base + 4);
    uint4 ov;
    ov.x = pack2bf(f0.x + cr[0], f0.y + cr[1]);
    ov.y = pack2bf(f0.z + cr[2], f0.w + cr[3]);
    ov.z = pack2bf(f1.x + cr[4], f1.y + cr[5]);
    ov.w = pack2bf(f1.z + cr[6], f1.w + cr[7]);
    *reinterpret_cast<uint4*>(X + base) = ov;
}

// ---------------------------------------------------------------
// LayerNorm over rows of width 4096; in bf16, gamma/beta fp32,
// out bf16 (OUTF32=false) or fp32 (OUTF32=true)
// ---------------------------------------------------------------
template <bool OUTF32>
__global__ __launch_bounds__(256)
void ln_rows(const USH* __restrict__ in, void* __restrict__ out,
             const float* __restrict__ g, const float* __restrict__ b)
{
    const int row = blockIdx.x;
    const USH* x = in + (size_t)row * 4096;
    const int tid = threadIdx.x;
    float vals[16];
    float s = 0.f, ss = 0.f;
#pragma unroll
    for (int i = 0; i < 16; i++) {
        float v = bf2f(x[tid + i * 256]);
        vals[i] = v; s += v; ss += v * v;
    }
#pragma unroll
    for (int off = 32; off > 0; off >>= 1) {
        s += __shfl_down(s, off, 64);
        ss += __shfl_down(ss, off, 64);
    }
    __shared__ float rs[4], rss[4];
    __shared__ float stats[2];
    if ((tid & 63) == 0) { rs[tid >> 6] = s; rss[tid >> 6] = ss; }
    __syncthreads();
    if (tid == 0) {
        float S = rs[0] + rs[1] + rs[2] + rs[3];
        float SS = rss[0] + rss[1] + rss[2] + rss[3];
        float mean = S * (1.0f / 4096.0f);
        float var = SS * (1.0f / 4096.0f) - mean * mean;
        stats[0] = mean;
        stats[1] = rsqrtf(var + 1e-5f);
    }
    __syncthreads();
    const float mean = stats[0], rstd = stats[1];
#pragma unroll
    for (int i = 0; i < 16; i++) {
        const int cidx = tid + i * 256;
        float v = (vals[i] - mean) * rstd * g[cidx] + b[cidx];
        if (OUTF32) ((float*)out)[(size_t)row * 4096 + cidx] = v;
        else ((USH*)out)[(size_t)row * 4096 + cidx] = f2bf(v);
    }
}

// ---------------------------------------------------------------
// softmax over 13824 per row (scores fp32 -> probs bf16)
// ---------------------------------------------------------------
__global__ __launch_bounds__(256)
void softmax_rows(const float* __restrict__ scores, USH* __restrict__ probs)
{
    const int row = blockIdx.x;   // h*128 + t
    const float* x = scores + (size_t)row * 13824;
    USH* p = probs + (size_t)row * 13824;
    const int tid = threadIdx.x;
    float mx = -1e30f;
    for (int i = tid; i < 13824; i += 256) mx = fmaxf(mx, x[i]);
#pragma unroll
    for (int off = 32; off > 0; off >>= 1) mx = fmaxf(mx, __shfl_down(mx, off, 64));
    __shared__ float rm[4];
    __shared__ float bm, bs;
    if ((tid & 63) == 0) rm[tid >> 6] = mx;
    __syncthreads();
    if (tid == 0) bm = fmaxf(fmaxf(rm[0], rm[1]), fmaxf(rm[2], rm[3]));
    __syncthreads();
    const float M = bm;
    float sum = 0.f;
    for (int i = tid; i < 13824; i += 256) sum += expf(x[i] - M);
#pragma unroll
    for (int off = 32; off > 0; off >>= 1) sum += __shfl_down(sum, off, 64);
    if ((tid & 63) == 0) rm[tid >> 6] = sum;
    __syncthreads();
    if (tid == 0) bs = 1.0f / (rm[0] + rm[1] + rm[2] + rm[3]);
    __syncthreads();
    const float inv = bs;
    for (int i = tid; i < 13824; i += 256) p[i] = f2bf(expf(x[i] - M) * inv);
}

// ---------------------------------------------------------------
// PV: att[t, h*512+d] = sum_s P[h,t,s] * V[s, h*512+d]
// grid (dchunk=8, tchunk=4, head=8); block: 32 t x 8 d-groups of 8
// ---------------------------------------------------------------
__global__ __launch_bounds__(256)
void pv_kernel(const USH* __restrict__ P, const USH* __restrict__ V,
               USH* __restrict__ att)
{
    const int h = blockIdx.z;
    const int d0 = blockIdx.x * 64;
    const int t0 = blockIdx.y * 32;
    const int tid = threadIdx.x;
    const int tl = tid >> 3;    // 0..31
    const int dg = tid & 7;     // d = d0 + dg*8 .. +8
    __shared__ USH Ps[32][72];
    __shared__ USH Vs[64][72];
    float acc[8] = {0.f, 0.f, 0.f, 0.f, 0.f, 0.f, 0.f, 0.f};

    for (int sc = 0; sc < 13824; sc += 64) {
        {
            const USH* pp = P + (size_t)(h * 128 + t0 + (tid >> 3)) * 13824 + sc + (tid & 7) * 8;
            uint4 v = *reinterpret_cast<const uint4*>(pp);
            *reinterpret_cast<uint4*>(&Ps[tid >> 3][(tid & 7) * 8]) = v;
        }
        {
            const USH* vp = V + (size_t)(sc + (tid >> 2)) * 4096 + h * 512 + d0 + (tid & 3) * 16;
            uint4 v0 = *reinterpret_cast<const uint4*>(vp);
            uint4 v1 = *reinterpret_cast<const uint4*>(vp + 8);
            *reinterpret_cast<uint4*>(&Vs[tid >> 2][(tid & 3) * 16]) = v0;
            *reinterpret_cast<uint4*>(&Vs[tid >> 2][(tid & 3) * 16 + 8]) = v1;
        }
        __syncthreads();
#pragma unroll 8
        for (int s8 = 0; s8 < 64; s8++) {
            float pv = bf2f(Ps[tl][s8]);
            uint4 raw = *reinterpret_cast<const uint4*>(&Vs[s8][dg * 8]);
            acc[0] += pv * bfbits2f(raw.x & 0xffffu);
            acc[1] += pv * bfbits2f(raw.x >> 16);
            acc[2] += pv * bfbits2f(raw.y & 0xffffu);
            acc[3] += pv * bfbits2f(raw.y >> 16);
            acc[4] += pv * bfbits2f(raw.z & 0xffffu);
            acc[5] += pv * bfbits2f(raw.z >> 16);
            acc[6] += pv * bfbits2f(raw.w & 0xffffu);
            acc[7] += pv * bfbits2f(raw.w >> 16);
        }
        __syncthreads();
    }
    USH* o = att + (size_t)(t0 + tl) * 4096 + h * 512 + d0 + dg * 8;
    uint4 ov;
    ov.x = pack2bf(acc[0], acc[1]);
    ov.y = pack2bf(acc[2], acc[3]);
    ov.z = pack2bf(acc[4], acc[5]);
    ov.w = pack2bf(acc[6], acc[7]);
    *reinterpret_cast<uint4*>(o) = ov;
}

// ---------------------------------------------------------------
extern "C" void kernel_launch(void* const* d_in, const int* in_sizes, int n_in,
                              void* d_out, int out_size, void* d_ws, size_t ws_size,
                              hipStream_t stream)
{
    const float* text = (const float*)d_in[0];
    const float* feats = (const float*)d_in[1];
    const float* W1w = (const float*)d_in[2];
    const float* W1b = (const float*)d_in[3];
    const float* Wcw = (const float*)d_in[4];
    const float* Wcb = (const float*)d_in[5];
    const float* Wiw = (const float*)d_in[6];
    const float* Wib = (const float*)d_in[7];
    const float* Wfw = (const float*)d_in[8];
    const float* Wfb = (const float*)d_in[9];
    const float* bc  = (const float*)d_in[10];
    const float* bi  = (const float*)d_in[11];
    const float* bfv = (const float*)d_in[12];
    const float* g1w = (const float*)d_in[13];
    const float* g1b = (const float*)d_in[14];
    const float* g2w = (const float*)d_in[15];
    const float* g2b = (const float*)d_in[16];
    const float* Wqw = (const float*)d_in[17];
    const float* Wqb = (const float*)d_in[18];
    const float* Wkw = (const float*)d_in[19];
    const float* Wkb = (const float*)d_in[20];
    const float* Wow = (const float*)d_in[21];
    const float* Wob = (const float*)d_in[22];
    const float* qng = (const float*)d_in[23];
    const float* qnb = (const float*)d_in[24];
    const float* kng = (const float*)d_in[25];
    const float* knb = (const float*)d_in[26];
    const float* ong = (const float*)d_in[27];
    const float* onb = (const float*)d_in[28];

    // ---- workspace layout (bump allocator, 256B aligned) ----
    char* base = (char*)d_ws;
    size_t off = 0;
    auto take = [&](size_t nbytes) -> char* {
        char* p = base + off;
        off += (nbytes + 255) & ~(size_t)255;
        return p;
    };
    const size_t BIG = (size_t)13824 * 4096 * 2;   // 113,246,208 B
    USH* P1 = (USH*)take(BIG);          // X, then K (in-place LN)
    USH* P2 = (USH*)take(BIG);          // H1; later overlaid: scores fp32 + probs bf16
    USH* P3 = (USH*)take(BIG);          // refreshed
    float* tg  = (float*)take(4096 * 4);
    float* yv  = (float*)take(24 * 4096 * 4);
    float* cst = (float*)take(4096 * 4);
    float* scs = (float*)take(4096 * 4);
    float* sv  = (float*)take(1024 * 4);
    float* pre = (float*)take(24 * 1024 * 4);
    float* ctx = (float*)take(24 * 4096 * 4);
    USH* textb = (USH*)take((size_t)128 * 4096 * 2);
    USH* Qb   = (USH*)take((size_t)128 * 4096 * 2);
    USH* attb = (USH*)take((size_t)128 * 4096 * 2);
    USH* opre = (USH*)take((size_t)128 * 4096 * 2);
    USH* wb   = (USH*)take((size_t)4096 * 4096 * 2);   // reused bf16 weight buffer
    float* scores = (float*)P2;                                   // 56,623,104 B
    USH* probs = (USH*)((char*)P2 + (size_t)8 * 128 * 13824 * 4); // + 28,311,552 B
    (void)ws_size; (void)in_sizes; (void)n_in; (void)out_size;

    // ---- 1. means + cell init + text->bf16 + recurrence-independent W1 part ----
    means_k<<<dim3(16, 26), 256, 0, stream>>>(text, feats, tg, yv, cst, scs);
    f32_to_bf16<<<256, 256, 0, stream>>>(text, textb);
    dsu_pre<<<1024, 256, 0, stream>>>(W1w, W1b, yv, tg, pre);

    // ---- 2. DSU recurrence (sequential over 24 layers) ----
    for (int l = 0; l < 24; l++) {
        dsu_s1<<<1024, 256, 0, stream>>>(W1w, scs, pre + (size_t)l * 1024, sv);
        dsu_s2<<<4096, 256, 0, stream>>>(Wcw, Wcb, Wiw, Wib, Wfw, Wfb, bc, bi, bfv,
                                         sv, cst, ctx + (size_t)l * 4096, scs);
    }

    // ---- 3. spatial gate (weights pre-converted to bf16, m97-style GEMM) ----
    make_x<<<27648, 256, 0, stream>>>(feats, ctx, P1);
    f32_to_bf16<<<8192, 256, 0, stream>>>(g1w, wb);
    gemm_bt<EPI_GELU, false><<<dim3(32, 108, 1), 256, 0, stream>>>(
        P1, 4096, 0, wb, 4096, 0, P2, 4096, 0, g1b, nullptr, 1.f, 4096);
    f32_to_bf16<<<8192, 256, 0, stream>>>(g2w, wb);
    gemm_bt<EPI_GATE, false><<<dim3(32, 108, 1), 256, 0, stream>>>(
        P2, 4096, 0, wb, 4096, 0, P3, 4096, 0, g2b, feats, 1.f, 4096);

    // ---- 4. K = LN(refreshed @ Wk^T + b) ----
    f32_to_bf16<<<8192, 256, 0, stream>>>(Wkw, wb);
    gemm_bt<EPI_PLAIN, false><<<dim3(32, 108, 1), 256, 0, stream>>>(
        P3, 4096, 0, wb, 4096, 0, P1, 4096, 0, Wkb, nullptr, 1.f, 4096);
    ln_rows<false><<<13824, 256, 0, stream>>>(P1, P1, kng, knb);

    // ---- 5. Q = LN(text @ Wq^T + b)  (tiny, keep fp32-W reg staging) ----
    gemm_bt<EPI_PLAIN, true><<<dim3(32, 1, 1), 256, 0, stream>>>(
        textb, 4096, 0, Wqw, 4096, 0, Qb, 4096, 0, Wqb, nullptr, 1.f, 4096);
    ln_rows<false><<<128, 256, 0, stream>>>(Qb, Qb, qng, qnb);

    // ---- 6. scores = Q K^T / sqrt(512*24), per head ----
    const float alpha = 0.00902109753f;  // 1/sqrt(512*24)
    gemm_bt<EPI_SCORES, false><<<dim3(108, 1, 8), 256, 0, stream>>>(
        Qb, 4096, 512, P1, 4096, 512, scores, 13824, (long long)128 * 13824,
        nullptr, nullptr, alpha, 512);

    // ---- 7. softmax + PV ----
    softmax_rows<<<1024, 256, 0, stream>>>(scores, probs);
    pv_kernel<<<dim3(8, 4, 8), 256, 0, stream>>>(probs, P3, attb);

    // ---- 8. out = LN(att @ Wo^T + b), fp32 out ----
    gemm_bt<EPI_PLAIN, true><<<dim3(32, 1, 1), 256, 0, stream>>>(
        attb, 4096, 0, Wow, 4096, 0, opre, 4096, 0, Wob, nullptr, 1.f, 4096);
    ln_rows<true><<<128, 256, 0, stream>>>(opre, (float*)d_out, ong, onb);
}

// Round 2
// 3949.505 us; speedup vs baseline: 1.3059x; 1.0912x over previous
//
#include <hip/hip_runtime.h>

#define USH unsigned short

// ---------- bf16 helpers (bit-exact, no __bf16 arithmetic) ----------
__device__ __forceinline__ float bf2f(USH u) {
    return __uint_as_float(((unsigned int)u) << 16);
}
__device__ __forceinline__ float bfbits2f(unsigned int b) {
    return __uint_as_float(b << 16);
}
__device__ __forceinline__ USH f2bf(float f) {
    unsigned int x = __float_as_uint(f);
    x += 0x7fffu + ((x >> 16) & 1u);   // RNE
    return (USH)(x >> 16);
}
__device__ __forceinline__ unsigned int pack2bf(float a, float b) {
    return (unsigned int)f2bf(a) | ((unsigned int)f2bf(b) << 16);
}
__device__ __forceinline__ float sigmoidf_(float x) { return 1.0f / (1.0f + expf(-x)); }

typedef __bf16 bf16x8 __attribute__((ext_vector_type(8)));
typedef float floatx4 __attribute__((ext_vector_type(4)));

// async global->LDS, 16B per lane, wave-uniform LDS base (dest = base + lane*16)
#define GLOAD_LDS16(g, l) __builtin_amdgcn_global_load_lds( \
    (const __attribute__((address_space(1))) void*)(g),     \
    (__attribute__((address_space(3))) void*)(l), 16, 0, 0)

// ---------------------------------------------------------------
// BT-GEMM: C[m,n] = epi( sum_k A[m,k] * W[n,k] + bias[n] )
// 128x128 tile, BK=32, linear LDS [128][32], global_load_lds width=16,
// 4 waves (2x2 of 64x64), 16x16x32 MFMA, DOUBLE-BUFFERED 2-phase loop:
//   stage(next buf) -> compute(cur buf) -> vmcnt(0)+barrier  (T3-minimum)
// so next-tile loads are in flight across the whole MFMA phase instead of
// draining inside the barrier (the m97 ~500TF stall at this shape).
// z decomposition: z1 = z/zdiv, z2 = z%zdiv; A += z1*sAz + z2*sAz2 etc.
// (used for split-K PV: z = head*8 + kchunk).
// C/D: col=lane&15, row=(lane>>4)*4+reg   [measured m89/m91]
// ---------------------------------------------------------------
enum { EPI_SCORES = 0, EPI_GELU = 1, EPI_GATE = 2, EPI_PLAIN = 3 };

template <int EPI, bool WF32>
__global__ __launch_bounds__(256)
void gemm_bt(const USH* __restrict__ A, int lda, long long sAz, long long sAz2, int zdiv,
             const void* __restrict__ Wv, int ldw, long long sWz, long long sWz2,
             void* __restrict__ Cout, int ldc, long long sCz,
             const float* __restrict__ bias, const float* __restrict__ fmul,
             float alpha, int Kd)
{
    __shared__ USH As[2][128 * 32];    // 2 x 8 KB
    __shared__ USH Ws[2][128 * 32];    // 2 x 8 KB
    const int z = blockIdx.z;
    const int z1 = z / zdiv;
    const int z2 = z % zdiv;
    A += (size_t)z1 * (size_t)sAz + (size_t)z2 * (size_t)sAz2;
    const USH* Wb = (const USH*)Wv + (size_t)z1 * (size_t)sWz + (size_t)z2 * (size_t)sWz2;
    const float* Wf = (const float*)Wv;   // WF32 callers use sWz=0
    const int m0 = blockIdx.y * 128;
    const int n0 = blockIdx.x * 128;
    const int tid = threadIdx.x;
    const int lane = tid & 63;
    const int wid = tid >> 6;
    const int wm = (wid >> 1) * 64;
    const int wn = (wid & 1) * 64;
    const int q = lane >> 4;
    const int r = lane & 15;

    floatx4 acc[4][4] = {};

    // --- global_load_lds staging geometry ---
    // chunk c = wid*2 + i covers rows [c*16, c*16+16); each issue = 1024 B.
    const int c0 = wid * 2;
    const int grow = c0 * 16 + (lane >> 2);
    const int gcol = (lane & 3) * 8;
    const USH* apA0 = A + (size_t)(m0 + grow) * lda + gcol;
    const USH* apA1 = apA0 + (size_t)16 * lda;
    USH* lA0 = &As[0][c0 * 512];
    USH* lA1 = &As[0][(c0 + 1) * 512];
    const USH* apW0 = Wb + (size_t)(n0 + grow) * ldw + gcol;
    const USH* apW1 = apW0 + (size_t)16 * ldw;
    USH* lW0 = &Ws[0][c0 * 512];
    USH* lW1 = &Ws[0][(c0 + 1) * 512];

    // --- WF32 reg-staging geometry (W only; tiny M=128 GEMMs) ---
    const int frow = tid >> 1;
    const int fcol = (tid & 1) * 16;
    const float* wpf = Wf + (size_t)(n0 + frow) * ldw + fcol;
    USH* wsw = &Ws[0][frow * 32 + fcol];

    auto stage = [&](int k0, int b) {
        GLOAD_LDS16(apA0 + k0, lA0 + b * 4096);
        GLOAD_LDS16(apA1 + k0, lA1 + b * 4096);
        if constexpr (WF32) {
            float4 f0 = *reinterpret_cast<const float4*>(wpf + k0);
            float4 f1 = *reinterpret_cast<const float4*>(wpf + k0 + 4);
            float4 f2 = *reinterpret_cast<const float4*>(wpf + k0 + 8);
            float4 f3 = *reinterpret_cast<const float4*>(wpf + k0 + 12);
            uint4 w0, w1;
            w0.x = pack2bf(f0.x, f0.y); w0.y = pack2bf(f0.z, f0.w);
            w0.z = pack2bf(f1.x, f1.y); w0.w = pack2bf(f1.z, f1.w);
            w1.x = pack2bf(f2.x, f2.y); w1.y = pack2bf(f2.z, f2.w);
            w1.z = pack2bf(f3.x, f3.y); w1.w = pack2bf(f3.z, f3.w);
            *reinterpret_cast<uint4*>(wsw + b * 4096) = w0;
            *reinterpret_cast<uint4*>(wsw + b * 4096 + 8) = w1;
        } else {
            GLOAD_LDS16(apW0 + k0, lW0 + b * 4096);
            GLOAD_LDS16(apW1 + k0, lW1 + b * 4096);
        }
    };

    auto compute = [&](const USH* Asb, const USH* Wsb) {
        bf16x8 af[4], wf4[4];
#pragma unroll
        for (int i = 0; i < 4; i++)
            af[i] = *reinterpret_cast<const bf16x8*>(&Asb[(wm + i * 16 + r) * 32 + q * 8]);
#pragma unroll
        for (int j = 0; j < 4; j++)
            wf4[j] = *reinterpret_cast<const bf16x8*>(&Wsb[(wn + j * 16 + r) * 32 + q * 8]);
#pragma unroll
        for (int i = 0; i < 4; i++)
#pragma unroll
            for (int j = 0; j < 4; j++)
                acc[i][j] = __builtin_amdgcn_mfma_f32_16x16x32_bf16(af[i], wf4[j], acc[i][j], 0, 0, 0);
    };

    // prologue: fill buffer 0
    stage(0, 0);
    asm volatile("s_waitcnt vmcnt(0) lgkmcnt(0)" ::: "memory");
    __builtin_amdgcn_s_barrier();

    // main loop, unrolled by 2 K-steps (all Kd are multiples of 64)
    for (int k0 = 0; k0 < Kd; k0 += 64) {
        stage(k0 + 32, 1);
        compute(&As[0][0], &Ws[0][0]);
        asm volatile("s_waitcnt vmcnt(0) lgkmcnt(0)" ::: "memory");
        __builtin_amdgcn_s_barrier();
        if (k0 + 64 < Kd) stage(k0 + 64, 0);
        compute(&As[1][0], &Ws[1][0]);
        if (k0 + 64 < Kd) {
            asm volatile("s_waitcnt vmcnt(0) lgkmcnt(0)" ::: "memory");
            __builtin_amdgcn_s_barrier();
        }
    }

#pragma unroll
    for (int j = 0; j < 4; j++) {
        const int col = n0 + wn + j * 16 + r;
        const float bv = (EPI == EPI_SCORES) ? 0.f : bias[col];
#pragma unroll
        for (int i = 0; i < 4; i++) {
            const int row0 = m0 + wm + i * 16 + q * 4;
#pragma unroll
            for (int rr = 0; rr < 4; rr++) {
                const int row = row0 + rr;
                float v = acc[i][j][rr];
                if (EPI == EPI_SCORES) {
                    ((float*)Cout)[(size_t)z * (size_t)sCz + (size_t)row * ldc + col] = v * alpha;
                } else if (EPI == EPI_GELU) {
                    v += bv;
                    float g = 0.5f * v * (1.0f + erff(v * 0.7071067811865475f));
                    ((USH*)Cout)[(size_t)row * ldc + col] = f2bf(g);
                } else if (EPI == EPI_GATE) {
                    v += bv;
                    float gate = 1.0f / (1.0f + expf(-v));
                    float o = gate * fmul[(size_t)row * ldc + col];
                    ((USH*)Cout)[(size_t)row * ldc + col] = f2bf(o);
                } else {
                    ((USH*)Cout)[(size_t)row * ldc + col] = f2bf(v + bv);
                }
            }
        }
    }
}

// ---------------------------------------------------------------
// means: z<24 -> y[z][d] = mean_n feats[z,n,d]; z==24 -> tg[d] = mean_t text
// z==25 -> init cell state (c=0, sigmoid(c)=0.5)
// ---------------------------------------------------------------
__global__ __launch_bounds__(256)
void means_k(const float* __restrict__ text, const float* __restrict__ feats,
             float* __restrict__ tg, float* __restrict__ yv, float* __restrict__ cst,
             float* __restrict__ scs)
{
    const int d = blockIdx.x * 256 + threadIdx.x;
    const int z = blockIdx.y;
    if (z < 24) {
        const float* f = feats + (size_t)z * 576 * 4096 + d;
        float s = 0.f;
        for (int n = 0; n < 576; n++) s += f[(size_t)n * 4096];
        yv[z * 4096 + d] = s * (1.0f / 576.0f);
    } else if (z == 24) {
        float s = 0.f;
        for (int t = 0; t < 128; t++) s += text[(size_t)t * 4096 + d];
        tg[d] = s * (1.0f / 128.0f);
    } else {
        cst[d] = 0.f;
        scs[d] = 0.5f;
    }
}

// ---------------------------------------------------------------
// f32 -> bf16 bulk convert (text, and the 3 big weight matrices)
// ---------------------------------------------------------------
__global__ __launch_bounds__(256)
void f32_to_bf16(const float* __restrict__ src, USH* __restrict__ dst)
{
    const size_t base = ((size_t)blockIdx.x * 256 + threadIdx.x) * 8;
    float4 f0 = *reinterpret_cast<const float4*>(src + base);
    float4 f1 = *reinterpret_cast<const float4*>(src + base + 4);
    uint4 ov;
    ov.x = pack2bf(f0.x, f0.y); ov.y = pack2bf(f0.z, f0.w);
    ov.z = pack2bf(f1.x, f1.y); ov.w = pack2bf(f1.z, f1.w);
    *reinterpret_cast<uint4*>(dst + base) = ov;
}

// ---------------------------------------------------------------
// bf16 transpose: dst[d][s] = src[s][d]; src 13824 x 4096
// 64x64 tiles, LDS staged
// ---------------------------------------------------------------
__global__ __launch_bounds__(256)
void transpose_bf16(const USH* __restrict__ src, USH* __restrict__ dst)
{
    __shared__ USH T[64][72];
    const int s0 = blockIdx.x * 64;   // 216
    const int d0 = blockIdx.y * 64;   // 64
    const int tid = threadIdx.x;
    const int rr = tid >> 3;          // 0..31
    const int c8 = (tid & 7) * 8;     // 0..56
#pragma unroll
    for (int i = 0; i < 2; i++) {
        const int row = rr + i * 32;
        uint4 v = *reinterpret_cast<const uint4*>(src + (size_t)(s0 + row) * 4096 + d0 + c8);
        *reinterpret_cast<uint4*>(&T[row][c8]) = v;
    }
    __syncthreads();
#pragma unroll
    for (int i = 0; i < 2; i++) {
        const int drow = rr + i * 32;
        USH tmp[8];
#pragma unroll
        for (int j = 0; j < 8; j++) tmp[j] = T[c8 + j][drow];
        *reinterpret_cast<uint4*>(dst + (size_t)(d0 + drow) * 13824 + s0 + c8) =
            *reinterpret_cast<const uint4*>(tmp);
    }
}

// ---------------------------------------------------------------
// PV split-K reduce: att[t][h*512+d] = bf16( sum_kc part[h*8+kc][t][d] )
// part: [64][128][512] fp32
// ---------------------------------------------------------------
__global__ __launch_bounds__(256)
void pv_reduce(const float* __restrict__ part, USH* __restrict__ att)
{
    const int idx = blockIdx.x * 256 + threadIdx.x;   // 131072 threads
    const size_t o = (size_t)idx * 4;
    const int t = (int)(o >> 12);
    const int col = (int)(o & 4095);
    const int h = col >> 9;
    const int d = col & 511;
    const float* p = part + (size_t)h * 8 * 65536 + t * 512 + d;
    float4 s = {0.f, 0.f, 0.f, 0.f};
#pragma unroll
    for (int kc = 0; kc < 8; kc++) {
        float4 v = *reinterpret_cast<const float4*>(p + (size_t)kc * 65536);
        s.x += v.x; s.y += v.y; s.z += v.z; s.w += v.w;
    }
    uint2 ov;
    ov.x = pack2bf(s.x, s.y);
    ov.y = pack2bf(s.z, s.w);
    *reinterpret_cast<uint2*>(att + o) = ov;
}

// ---------------------------------------------------------------
// DSU precompute (recurrence-independent 2/3 of W1 matvec):
// pre[l,r] = W1[r,4096:8192].y_l + W1[r,8192:12288].tg + W1_b[r]
// ---------------------------------------------------------------
__global__ __launch_bounds__(256)
void dsu_pre(const float* __restrict__ W1w, const float* __restrict__ W1b,
             const float* __restrict__ yv, const float* __restrict__ tg,
             float* __restrict__ pre)
{
    const int rrow = blockIdx.x;
    const float* w = W1w + (size_t)rrow * 12288;
    const int tid = threadIdx.x;
    float wy[16];
    float at = 0.f;
#pragma unroll
    for (int i = 0; i < 16; i++) {
        const int k = tid + i * 256;
        wy[i] = w[4096 + k];
        at += w[8192 + k] * tg[k];
    }
#pragma unroll
    for (int o = 32; o > 0; o >>= 1) at += __shfl_down(at, o, 64);
    __shared__ float red[4];
    __shared__ float tgs;
    if ((tid & 63) == 0) red[tid >> 6] = at;
    __syncthreads();
    if (tid == 0) tgs = red[0] + red[1] + red[2] + red[3] + W1b[rrow];
    for (int l = 0; l < 24; l++) {
        const float* y = yv + (size_t)l * 4096;
        float a = 0.f;
#pragma unroll
        for (int i = 0; i < 16; i++) a += wy[i] * y[tid + i * 256];
#pragma unroll
        for (int o = 32; o > 0; o >>= 1) a += __shfl_down(a, o, 64);
        __syncthreads();
        if ((tid & 63) == 0) red[tid >> 6] = a;
        __syncthreads();
        if (tid == 0) pre[l * 1024 + rrow] = red[0] + red[1] + red[2] + red[3] + tgs;
    }
}

// ---------------------------------------------------------------
// DSU step 1 (sequential part only): s[r] = relu(W1[r,0:4096].sig(c) + pre[l,r])
// ---------------------------------------------------------------
__global__ __launch_bounds__(256)
void dsu_s1(const float* __restrict__ W1w, const float* __restrict__ scs,
            const float* __restrict__ pre_l, float* __restrict__ sv)
{
    const int rrow = blockIdx.x;
    const float* w = W1w + (size_t)rrow * 12288;
    const int tid = threadIdx.x;
    float acc = 0.f;
#pragma unroll
    for (int i = 0; i < 16; i++) {
        const int k = tid + i * 256;
        acc += w[k] * scs[k];
    }
#pragma unroll
    for (int o = 32; o > 0; o >>= 1) acc += __shfl_down(acc, o, 64);
    __shared__ float red[4];
    if ((tid & 63) == 0) red[tid >> 6] = acc;
    __syncthreads();
    if (tid == 0) {
        float t = red[0] + red[1] + red[2] + red[3] + pre_l[rrow];
        sv[rrow] = fmaxf(t, 0.f);
    }
}

// ---------------------------------------------------------------
// DSU step 2: gates + cell update + ctx write + cached sigmoid(c)
// ---------------------------------------------------------------
__global__ __launch_bounds__(256)
void dsu_s2(const float* __restrict__ Wc, const float* __restrict__ Wcb,
            const float* __restrict__ Wi, const float* __restrict__ Wib,
            const float* __restrict__ Wf, const float* __restrict__ Wfb,
            const float* __restrict__ bc, const float* __restrict__ bi,
            const float* __restrict__ bfv,
             const float* __restrict__ sv, float* __restrict__ c,
             float* __restrict__ ctx_l, float* __restrict__ scs)
{
    const int d = blockIdx.x;
    const int tid = threadIdx.x;
    float a0 = 0.f, a1 = 0.f, a2 = 0.f;
    for (int k = tid; k < 1024; k += 256) {
        float s = sv[k];
        a0 += Wc[(size_t)d * 1024 + k] * s;
        a1 += Wi[(size_t)d * 1024 + k] * s;
        a2 += Wf[(size_t)d * 1024 + k] * s;
    }
#pragma unroll
    for (int o = 32; o > 0; o >>= 1) {
        a0 += __shfl_down(a0, o, 64);
        a1 += __shfl_down(a1, o, 64);
        a2 += __shfl_down(a2, o, 64);
    }
    __shared__ float red[3][4];
    if ((tid & 63) == 0) {
        red[0][tid >> 6] = a0; red[1][tid >> 6] = a1; red[2][tid >> 6] = a2;
    }
    __syncthreads();
    if (tid == 0) {
        float A0 = red[0][0] + red[0][1] + red[0][2] + red[0][3];
        float A1 = red[1][0] + red[1][1] + red[1][2] + red[1][3];
        float A2 = red[2][0] + red[2][1] + red[2][2] + red[2][3];
        float ct = tanhf(A0 + Wcb[d] + bc[d]);
        float ig = sigmoidf_(A1 + Wib[d] + bi[d]);
        float fg = sigmoidf_(A2 + Wfb[d] + bfv[d]);
        float cn = fg * c[d] + ig * ct;
        c[d] = cn;
        ctx_l[d] = cn;
        scs[d] = sigmoidf_(cn);
    }
}

// ---------------------------------------------------------------
// X = bf16( feats + ctx[layer] )   (8 elements/thread); feats fp32
// ---------------------------------------------------------------
__global__ __launch_bounds__(256)
void make_x(const float* __restrict__ feats, const float* __restrict__ ctx,
            USH* __restrict__ X)
{
    const size_t base = ((size_t)blockIdx.x * 256 + threadIdx.x) * 8;
    const int row = (int)(base >> 12);
    const int l = row / 576;
    const float* cr = ctx + (size_t)l * 4096 + (base & 4095);
    float4 f0 = *reinterpret_cast<const float4*>(feats + base);
    float4 f1 = *reinterpret_cast<const float4*>(feats + base + 4);
    uint4 ov;
    ov.x = pack2bf(f0.x + cr[0], f0.y + cr[1]);
    ov.y = pack2bf(f0.z + cr[2], f0.w + cr[3]);
    ov.z = pack2bf(f1.x + cr[4], f1.y + cr[5]);
    ov.w = pack2bf(f1.z + cr[6], f1.w + cr[7]);
    *reinterpret_cast<uint4*>(X + base) = ov;
}

// ---------------------------------------------------------------
// LayerNorm over rows of width 4096; in bf16, gamma/beta fp32,
// out bf16 (OUTF32=false) or fp32 (OUTF32=true)
// ---------------------------------------------------------------
template <bool OUTF32>
__global__ __launch_bounds__(256)
void ln_rows(const USH* __restrict__ in, void* __restrict__ out,
             const float* __restrict__ g, const float* __restrict__ b)
{
    const int row = blockIdx.x;
    const USH* x = in + (size_t)row * 4096;
    const int tid = threadIdx.x;
    float vals[16];
    float s = 0.f, ss = 0.f;
#pragma unroll
    for (int i = 0; i < 16; i++) {
        float v = bf2f(x[tid + i * 256]);
        vals[i] = v; s += v; ss += v * v;
    }
#pragma unroll
    for (int off = 32; off > 0; off >>= 1) {
        s += __shfl_down(s, off, 64);
        ss += __shfl_down(ss, off, 64);
    }
    __shared__ float rs[4], rss[4];
    __shared__ float stats[2];
    if ((tid & 63) == 0) { rs[tid >> 6] = s; rss[tid >> 6] = ss; }
    __syncthreads();
    if (tid == 0) {
        float S = rs[0] + rs[1] + rs[2] + rs[3];
        float SS = rss[0] + rss[1] + rss[2] + rss[3];
        float mean = S * (1.0f / 4096.0f);
        float var = SS * (1.0f / 4096.0f) - mean * mean;
        stats[0] = mean;
        stats[1] = rsqrtf(var + 1e-5f);
    }
    __syncthreads();
    const float mean = stats[0], rstd = stats[1];
#pragma unroll
    for (int i = 0; i < 16; i++) {
        const int cidx = tid + i * 256;
        float v = (vals[i] - mean) * rstd * g[cidx] + b[cidx];
        if (OUTF32) ((float*)out)[(size_t)row * 4096 + cidx] = v;
        else ((USH*)out)[(size_t)row * 4096 + cidx] = f2bf(v);
    }
}

// ---------------------------------------------------------------
// softmax over 13824 per row (scores fp32 -> probs bf16)
// ---------------------------------------------------------------
__global__ __launch_bounds__(256)
void softmax_rows(const float* __restrict__ scores, USH* __restrict__ probs)
{
    const int row = blockIdx.x;   // h*128 + t
    const float* x = scores + (size_t)row * 13824;
    USH* p = probs + (size_t)row * 13824;
    const int tid = threadIdx.x;
    float mx = -1e30f;
    for (int i = tid; i < 13824; i += 256) mx = fmaxf(mx, x[i]);
#pragma unroll
    for (int off = 32; off > 0; off >>= 1) mx = fmaxf(mx, __shfl_down(mx, off, 64));
    __shared__ float rm[4];
    __shared__ float bm, bs;
    if ((tid & 63) == 0) rm[tid >> 6] = mx;
    __syncthreads();
    if (tid == 0) bm = fmaxf(fmaxf(rm[0], rm[1]), fmaxf(rm[2], rm[3]));
    __syncthreads();
    const float M = bm;
    float sum = 0.f;
    for (int i = tid; i < 13824; i += 256) sum += expf(x[i] - M);
#pragma unroll
    for (int off = 32; off > 0; off >>= 1) sum += __shfl_down(sum, off, 64);
    if ((tid & 63) == 0) rm[tid >> 6] = sum;
    __syncthreads();
    if (tid == 0) bs = 1.0f / (rm[0] + rm[1] + rm[2] + rm[3]);
    __syncthreads();
    const float inv = bs;
    for (int i = tid; i < 13824; i += 256) p[i] = f2bf(expf(x[i] - M) * inv);
}

// ---------------------------------------------------------------
extern "C" void kernel_launch(void* const* d_in, const int* in_sizes, int n_in,
                              void* d_out, int out_size, void* d_ws, size_t ws_size,
                              hipStream_t stream)
{
    const float* text = (const float*)d_in[0];
    const float* feats = (const float*)d_in[1];
    const float* W1w = (const float*)d_in[2];
    const float* W1b = (const float*)d_in[3];
    const float* Wcw = (const float*)d_in[4];
    const float* Wcb = (const float*)d_in[5];
    const float* Wiw = (const float*)d_in[6];
    const float* Wib = (const float*)d_in[7];
    const float* Wfw = (const float*)d_in[8];
    const float* Wfb = (const float*)d_in[9];
    const float* bc  = (const float*)d_in[10];
    const float* bi  = (const float*)d_in[11];
    const float* bfv = (const float*)d_in[12];
    const float* g1w = (const float*)d_in[13];
    const float* g1b = (const float*)d_in[14];
    const float* g2w = (const float*)d_in[15];
    const float* g2b = (const float*)d_in[16];
    const float* Wqw = (const float*)d_in[17];
    const float* Wqb = (const float*)d_in[18];
    const float* Wkw = (const float*)d_in[19];
    const float* Wkb = (const float*)d_in[20];
    const float* Wow = (const float*)d_in[21];
    const float* Wob = (const float*)d_in[22];
    const float* qng = (const float*)d_in[23];
    const float* qnb = (const float*)d_in[24];
    const float* kng = (const float*)d_in[25];
    const float* knb = (const float*)d_in[26];
    const float* ong = (const float*)d_in[27];
    const float* onb = (const float*)d_in[28];

    // ---- workspace layout (bump allocator, 256B aligned) ----
    char* base = (char*)d_ws;
    size_t off = 0;
    auto take = [&](size_t nbytes) -> char* {
        char* p = base + off;
        off += (nbytes + 255) & ~(size_t)255;
        return p;
    };
    const size_t BIG = (size_t)13824 * 4096 * 2;   // 113,246,208 B
    USH* P1 = (USH*)take(BIG);          // X -> K (LN in place) -> V^T
    USH* P2 = (USH*)take(BIG);          // H1; later: scores fp32 + probs bf16
    USH* P3 = (USH*)take(BIG);          // refreshed (V)
    float* tg  = (float*)take(4096 * 4);
    float* yv  = (float*)take(24 * 4096 * 4);
    float* cst = (float*)take(4096 * 4);
    float* scs = (float*)take(4096 * 4);
    float* sv  = (float*)take(1024 * 4);
    float* pre = (float*)take(24 * 1024 * 4);
    float* ctx = (float*)take(24 * 4096 * 4);
    USH* textb = (USH*)take((size_t)128 * 4096 * 2);
    USH* Qb   = (USH*)take((size_t)128 * 4096 * 2);
    USH* attb = (USH*)take((size_t)128 * 4096 * 2);
    USH* opre = (USH*)take((size_t)128 * 4096 * 2);
    USH* wb   = (USH*)take((size_t)4096 * 4096 * 2);   // bf16 weights; later PV fp32 partials
    float* scores = (float*)P2;                                   // 56,623,104 B
    USH* probs = (USH*)((char*)P2 + (size_t)8 * 128 * 13824 * 4); // + 28,311,552 B
    USH* vT = P1;                        // V^T overlay after K is consumed
    float* pvpart = (float*)wb;          // 64*128*512*4 = 16.8 MB (fits in wb)
    (void)ws_size; (void)in_sizes; (void)n_in; (void)out_size;

    // ---- 1. means + cell init + text->bf16 + recurrence-independent W1 part ----
    means_k<<<dim3(16, 26), 256, 0, stream>>>(text, feats, tg, yv, cst, scs);
    f32_to_bf16<<<256, 256, 0, stream>>>(text, textb);
    dsu_pre<<<1024, 256, 0, stream>>>(W1w, W1b, yv, tg, pre);

    // ---- 2. DSU recurrence (sequential over 24 layers) ----
    for (int l = 0; l < 24; l++) {
        dsu_s1<<<1024, 256, 0, stream>>>(W1w, scs, pre + (size_t)l * 1024, sv);
        dsu_s2<<<4096, 256, 0, stream>>>(Wcw, Wcb, Wiw, Wib, Wfw, Wfb, bc, bi, bfv,
                                         sv, cst, ctx + (size_t)l * 4096, scs);
    }

    // ---- 3. spatial gate (bf16 weights, dbuf GEMM) ----
    make_x<<<27648, 256, 0, stream>>>(feats, ctx, P1);
    f32_to_bf16<<<8192, 256, 0, stream>>>(g1w, wb);
    gemm_bt<EPI_GELU, false><<<dim3(32, 108, 1), 256, 0, stream>>>(
        P1, 4096, 0, 0, 1, wb, 4096, 0, 0, P2, 4096, 0, g1b, nullptr, 1.f, 4096);
    f32_to_bf16<<<8192, 256, 0, stream>>>(g2w, wb);
    gemm_bt<EPI_GATE, false><<<dim3(32, 108, 1), 256, 0, stream>>>(
        P2, 4096, 0, 0, 1, wb, 4096, 0, 0, P3, 4096, 0, g2b, feats, 1.f, 4096);

    // ---- 4. K = LN(refreshed @ Wk^T + b) ----
    f32_to_bf16<<<8192, 256, 0, stream>>>(Wkw, wb);
    gemm_bt<EPI_PLAIN, false><<<dim3(32, 108, 1), 256, 0, stream>>>(
        P3, 4096, 0, 0, 1, wb, 4096, 0, 0, P1, 4096, 0, Wkb, nullptr, 1.f, 4096);
    ln_rows<false><<<13824, 256, 0, stream>>>(P1, P1, kng, knb);

    // ---- 5. Q = LN(text @ Wq^T + b)  (tiny, fp32-W reg staging) ----
    gemm_bt<EPI_PLAIN, true><<<dim3(32, 1, 1), 256, 0, stream>>>(
        textb, 4096, 0, 0, 1, Wqw, 4096, 0, 0, Qb, 4096, 0, Wqb, nullptr, 1.f, 4096);
    ln_rows<false><<<128, 256, 0, stream>>>(Qb, Qb, qng, qnb);

    // ---- 6. scores = Q K^T / sqrt(512*24), per head ----
    const float alpha = 0.00902109753f;  // 1/sqrt(512*24)
    gemm_bt<EPI_SCORES, false><<<dim3(108, 1, 8), 256, 0, stream>>>(
        Qb, 4096, 512, 0, 1, P1, 4096, 512, 0, scores, 13824, (long long)128 * 13824,
        nullptr, nullptr, alpha, 512);

    // ---- 7. V^T (P3 -> P1, K no longer needed), softmax, PV via split-K MFMA ----
    transpose_bf16<<<dim3(216, 64), 256, 0, stream>>>(P3, vT);
    softmax_rows<<<1024, 256, 0, stream>>>(scores, probs);
    // z = head*8 + kchunk; A = probs[head] col-offset kc*1728; W = vT rows head*512.. col-offset kc*1728
    gemm_bt<EPI_SCORES, false><<<dim3(4, 1, 64), 256, 0, stream>>>(
        probs, 13824, (long long)128 * 13824, 1728, 8,
        vT, 13824, (long long)512 * 13824, 1728,
        pvpart, 512, 65536,
        nullptr, nullptr, 1.0f, 1728);
    pv_reduce<<<512, 256, 0, stream>>>(pvpart, attb);

    // ---- 8. out = LN(att @ Wo^T + b), fp32 out ----
    gemm_bt<EPI_PLAIN, true><<<dim3(32, 1, 1), 256, 0, stream>>>(
        attb, 4096, 0, 0, 1, Wow, 4096, 0, 0, opre, 4096, 0, Wob, nullptr, 1.f, 4096);
    ln_rows<true><<<128, 256, 0, stream>>>(opre, (float*)d_out, ong, onb);
}

// Round 4
// 3657.232 us; speedup vs baseline: 1.4103x; 1.0799x over previous
//
#include <hip/hip_runtime.h>

#define USH unsigned short

// ---------- bf16 helpers (bit-exact, no __bf16 arithmetic) ----------
__device__ __forceinline__ float bf2f(USH u) {
    return __uint_as_float(((unsigned int)u) << 16);
}
__device__ __forceinline__ float bfbits2f(unsigned int b) {
    return __uint_as_float(b << 16);
}
__device__ __forceinline__ USH f2bf(float f) {
    unsigned int x = __float_as_uint(f);
    x += 0x7fffu + ((x >> 16) & 1u);   // RNE
    return (USH)(x >> 16);
}
__device__ __forceinline__ unsigned int pack2bf(float a, float b) {
    return (unsigned int)f2bf(a) | ((unsigned int)f2bf(b) << 16);
}
__device__ __forceinline__ float sigmoidf_(float x) { return 1.0f / (1.0f + expf(-x)); }

typedef __bf16 bf16x8 __attribute__((ext_vector_type(8)));
typedef float floatx4 __attribute__((ext_vector_type(4)));

// async global->LDS, 16B per lane, wave-uniform LDS base (dest = base + lane*16)
#define GLOAD_LDS16(g, l) __builtin_amdgcn_global_load_lds( \
    (const __attribute__((address_space(1))) void*)(g),     \
    (__attribute__((address_space(3))) void*)(l), 16, 0, 0)

enum { EPI_SCORES = 0, EPI_GELU = 1, EPI_GATE = 2, EPI_PLAIN = 3 };

// ===============================================================
// gemm256: C[m,n] = epi( sum_k A[m,k]*W[n,k] + bias[n] ), both bf16.
// M = Mtiles*256 (13824), N = 4096 (16 tiles), K = Kd (4096).
// BM=BN=256, BK=64, 512 threads = 8 waves (2M x 4N), per-wave out 128x64.
// LDS 128 KiB: As/Ws = 2 bufs x 2 halves x [128][64] bf16.
// Per K-tile: 4 phases; phase = {stage 2 half-tiles of t+1 | 12 ds_read_b128
// | setprio(1) 16 MFMA setprio(0)}; one __syncthreads() per K-tile.
// T2 swizzle (both-sides, rule #21): logical (row, c16) lives at LDS slot
// c16 ^ (row&7); global source col pre-swizzled, ds_read applies same XOR.
// T1: bn-chunked XCD swizzle (bn = 2*(bid&7) + (j&1)) -> per-XCD W slice
// = 2 panels = 4MB = L2-resident.
// Fragment/epilogue conventions identical to the validated 128^2 kernel:
// A-frag lane holds A[m=lane&15][k=(lane>>4)*8+j]; C/D col=lane&15,
// row=(lane>>4)*4+reg  [measured m89/m91].
// ===============================================================
template <int QA, int QB>
__device__ __forceinline__ void phase256(const USH* __restrict__ Ab,
                                         const USH* __restrict__ Bb,
                                         floatx4 (&acc)[8][4],
                                         int q, int r, int wn)
{
    bf16x8 af[4][2], wf[2][2];
#pragma unroll
    for (int ii = 0; ii < 4; ii++) {
        const int row = (QA * 4 + ii) * 16 + r;
#pragma unroll
        for (int ks = 0; ks < 2; ks++)
            af[ii][ks] = *reinterpret_cast<const bf16x8*>(
                Ab + row * 64 + (((q + ks * 4) ^ (r & 7)) * 8));
    }
#pragma unroll
    for (int jj = 0; jj < 2; jj++) {
        const int row = (wn & 1) * 64 + (QB * 2 + jj) * 16 + r;
#pragma unroll
        for (int ks = 0; ks < 2; ks++)
            wf[jj][ks] = *reinterpret_cast<const bf16x8*>(
                Bb + row * 64 + (((q + ks * 4) ^ (r & 7)) * 8));
    }
    __builtin_amdgcn_s_setprio(1);
#pragma unroll
    for (int ii = 0; ii < 4; ii++)
#pragma unroll
        for (int jj = 0; jj < 2; jj++) {
            acc[QA * 4 + ii][QB * 2 + jj] = __builtin_amdgcn_mfma_f32_16x16x32_bf16(
                af[ii][0], wf[jj][0], acc[QA * 4 + ii][QB * 2 + jj], 0, 0, 0);
            acc[QA * 4 + ii][QB * 2 + jj] = __builtin_amdgcn_mfma_f32_16x16x32_bf16(
                af[ii][1], wf[jj][1], acc[QA * 4 + ii][QB * 2 + jj], 0, 0, 0);
        }
    __builtin_amdgcn_s_setprio(0);
}

template <int EPI>
__global__ __launch_bounds__(512, 2)
void gemm256(const USH* __restrict__ A, const USH* __restrict__ W,
             void* __restrict__ Cout, const float* __restrict__ bias,
             const float* __restrict__ fmul, int Kd)
{
    __shared__ __align__(16) USH As[32768];   // [buf][half][128][64]
    __shared__ __align__(16) USH Ws[32768];

    // T1 bn-chunk XCD swizzle (grid = Mtiles*16, Mtiles*16 % 8 == 0)
    const int bid = blockIdx.x;
    const int xcd = bid & 7;
    const int j = bid >> 3;
    const int bn = xcd * 2 + (j & 1);
    const int bm = j >> 1;
    const int m0 = bm * 256, n0 = bn * 256;

    const int tid = threadIdx.x;
    const int lane = tid & 63;
    const int wid = tid >> 6;      // 0..7
    const int wm = wid >> 2;       // 0..1: A-half
    const int wn = wid & 3;        // 0..3
    const int bh = wn >> 1;        // B-half
    const int q = lane >> 4, r = lane & 15;

    floatx4 acc[8][4] = {};

    // staging geometry: per half, 16 segs of 8 rows; wave w covers segs {2w, 2w+1}.
    // lane l -> row seg*8 + (l>>3); source col16 pre-swizzled: (l&7)^(l>>3).
    const int sl = lane >> 3;
    const int sc = ((lane & 7) ^ sl) * 8;
    const USH* gA[2][2]; const USH* gW[2][2];
    USH* lA[2][2]; USH* lW[2][2];
#pragma unroll
    for (int h = 0; h < 2; h++)
#pragma unroll
        for (int i = 0; i < 2; i++) {
            const int seg = wid * 2 + i;
            gA[h][i] = A + (size_t)(m0 + h * 128 + seg * 8 + sl) * 4096 + sc;
            gW[h][i] = W + (size_t)(n0 + h * 128 + seg * 8 + sl) * 4096 + sc;
            lA[h][i] = As + h * 8192 + seg * 512;
            lW[h][i] = Ws + h * 8192 + seg * 512;
        }

    // prologue: stage K-tile 0 into buf 0
#pragma unroll
    for (int h = 0; h < 2; h++)
#pragma unroll
        for (int i = 0; i < 2; i++) {
            GLOAD_LDS16(gA[h][i], lA[h][i]);
            GLOAD_LDS16(gW[h][i], lW[h][i]);
        }
    __syncthreads();

    const int nt = Kd >> 6;
    for (int t = 0; t < nt; t++) {
        const int p = t & 1;
        const USH* Ab = As + wm * 8192 + p * 16384;
        const USH* Bb = Ws + bh * 8192 + p * 16384;
        const int ko = (t + 1) * 64;
        const int bo = (p ^ 1) * 16384;
        const bool st = (t + 1 < nt);
        if (st) {
            GLOAD_LDS16(gA[0][0] + ko, lA[0][0] + bo);
            GLOAD_LDS16(gA[0][1] + ko, lA[0][1] + bo);
            GLOAD_LDS16(gA[1][0] + ko, lA[1][0] + bo);
            GLOAD_LDS16(gA[1][1] + ko, lA[1][1] + bo);
        }
        phase256<0, 0>(Ab, Bb, acc, q, r, wn);
        if (st) {
            GLOAD_LDS16(gW[0][0] + ko, lW[0][0] + bo);
            GLOAD_LDS16(gW[0][1] + ko, lW[0][1] + bo);
            GLOAD_LDS16(gW[1][0] + ko, lW[1][0] + bo);
            GLOAD_LDS16(gW[1][1] + ko, lW[1][1] + bo);
        }
        phase256<0, 1>(Ab, Bb, acc, q, r, wn);
        phase256<1, 0>(Ab, Bb, acc, q, r, wn);
        phase256<1, 1>(Ab, Bb, acc, q, r, wn);
        __syncthreads();
    }

#pragma unroll
    for (int jt = 0; jt < 4; jt++) {
        const int col = n0 + wn * 64 + jt * 16 + r;
        const float bv = bias[col];
#pragma unroll
        for (int i = 0; i < 8; i++) {
            const int row0 = m0 + wm * 128 + i * 16 + q * 4;
#pragma unroll
            for (int rr = 0; rr < 4; rr++) {
                const int row = row0 + rr;
                float v = acc[i][jt][rr] + bv;
                if (EPI == EPI_GELU) {
                    float g = 0.5f * v * (1.0f + erff(v * 0.7071067811865475f));
                    ((USH*)Cout)[(size_t)row * 4096 + col] = f2bf(g);
                } else if (EPI == EPI_GATE) {
                    float gate = 1.0f / (1.0f + expf(-v));
                    float o = gate * fmul[(size_t)row * 4096 + col];
                    ((USH*)Cout)[(size_t)row * 4096 + col] = f2bf(o);
                } else {
                    ((USH*)Cout)[(size_t)row * 4096 + col] = f2bf(v);
                }
            }
        }
    }
}

// ---------------------------------------------------------------
// BT-GEMM (128^2, validated): kept for QK / PV / Q / O shapes.
// ---------------------------------------------------------------
template <int EPI, bool WF32>
__global__ __launch_bounds__(256)
void gemm_bt(const USH* __restrict__ A, int lda, long long sAz, long long sAz2, int zdiv,
             const void* __restrict__ Wv, int ldw, long long sWz, long long sWz2,
             void* __restrict__ Cout, int ldc, long long sCz,
             const float* __restrict__ bias, const float* __restrict__ fmul,
             float alpha, int Kd)
{
    __shared__ USH As[2][128 * 32];    // 2 x 8 KB
    __shared__ USH Ws[2][128 * 32];    // 2 x 8 KB
    const int z = blockIdx.z;
    const int z1 = z / zdiv;
    const int z2 = z % zdiv;
    A += (size_t)z1 * (size_t)sAz + (size_t)z2 * (size_t)sAz2;
    const USH* Wb = (const USH*)Wv + (size_t)z1 * (size_t)sWz + (size_t)z2 * (size_t)sWz2;
    const float* Wf = (const float*)Wv;   // WF32 callers use sWz=0
    const int m0 = blockIdx.y * 128;
    const int n0 = blockIdx.x * 128;
    const int tid = threadIdx.x;
    const int lane = tid & 63;
    const int wid = tid >> 6;
    const int wm = (wid >> 1) * 64;
    const int wn = (wid & 1) * 64;
    const int q = lane >> 4;
    const int r = lane & 15;

    floatx4 acc[4][4] = {};

    const int c0 = wid * 2;
    const int grow = c0 * 16 + (lane >> 2);
    const int gcol = (lane & 3) * 8;
    const USH* apA0 = A + (size_t)(m0 + grow) * lda + gcol;
    const USH* apA1 = apA0 + (size_t)16 * lda;
    USH* lA0 = &As[0][c0 * 512];
    USH* lA1 = &As[0][(c0 + 1) * 512];
    const USH* apW0 = Wb + (size_t)(n0 + grow) * ldw + gcol;
    const USH* apW1 = apW0 + (size_t)16 * ldw;
    USH* lW0 = &Ws[0][c0 * 512];
    USH* lW1 = &Ws[0][(c0 + 1) * 512];

    const int frow = tid >> 1;
    const int fcol = (tid & 1) * 16;
    const float* wpf = Wf + (size_t)(n0 + frow) * ldw + fcol;
    USH* wsw = &Ws[0][frow * 32 + fcol];

    auto stage = [&](int k0, int b) {
        GLOAD_LDS16(apA0 + k0, lA0 + b * 4096);
        GLOAD_LDS16(apA1 + k0, lA1 + b * 4096);
        if constexpr (WF32) {
            float4 f0 = *reinterpret_cast<const float4*>(wpf + k0);
            float4 f1 = *reinterpret_cast<const float4*>(wpf + k0 + 4);
            float4 f2 = *reinterpret_cast<const float4*>(wpf + k0 + 8);
            float4 f3 = *reinterpret_cast<const float4*>(wpf + k0 + 12);
            uint4 w0, w1;
            w0.x = pack2bf(f0.x, f0.y); w0.y = pack2bf(f0.z, f0.w);
            w0.z = pack2bf(f1.x, f1.y); w0.w = pack2bf(f1.z, f1.w);
            w1.x = pack2bf(f2.x, f2.y); w1.y = pack2bf(f2.z, f2.w);
            w1.z = pack2bf(f3.x, f3.y); w1.w = pack2bf(f3.z, f3.w);
            *reinterpret_cast<uint4*>(wsw + b * 4096) = w0;
            *reinterpret_cast<uint4*>(wsw + b * 4096 + 8) = w1;
        } else {
            GLOAD_LDS16(apW0 + k0, lW0 + b * 4096);
            GLOAD_LDS16(apW1 + k0, lW1 + b * 4096);
        }
    };

    auto compute = [&](const USH* Asb, const USH* Wsb) {
        bf16x8 af[4], wf4[4];
#pragma unroll
        for (int i = 0; i < 4; i++)
            af[i] = *reinterpret_cast<const bf16x8*>(&Asb[(wm + i * 16 + r) * 32 + q * 8]);
#pragma unroll
        for (int j = 0; j < 4; j++)
            wf4[j] = *reinterpret_cast<const bf16x8*>(&Wsb[(wn + j * 16 + r) * 32 + q * 8]);
#pragma unroll
        for (int i = 0; i < 4; i++)
#pragma unroll
            for (int j = 0; j < 4; j++)
                acc[i][j] = __builtin_amdgcn_mfma_f32_16x16x32_bf16(af[i], wf4[j], acc[i][j], 0, 0, 0);
    };

    stage(0, 0);
    asm volatile("s_waitcnt vmcnt(0) lgkmcnt(0)" ::: "memory");
    __builtin_amdgcn_s_barrier();

    for (int k0 = 0; k0 < Kd; k0 += 64) {
        stage(k0 + 32, 1);
        compute(&As[0][0], &Ws[0][0]);
        asm volatile("s_waitcnt vmcnt(0) lgkmcnt(0)" ::: "memory");
        __builtin_amdgcn_s_barrier();
        if (k0 + 64 < Kd) stage(k0 + 64, 0);
        compute(&As[1][0], &Ws[1][0]);
        if (k0 + 64 < Kd) {
            asm volatile("s_waitcnt vmcnt(0) lgkmcnt(0)" ::: "memory");
            __builtin_amdgcn_s_barrier();
        }
    }

#pragma unroll
    for (int j = 0; j < 4; j++) {
        const int col = n0 + wn + j * 16 + r;
        const float bv = (EPI == EPI_SCORES) ? 0.f : bias[col];
#pragma unroll
        for (int i = 0; i < 4; i++) {
            const int row0 = m0 + wm + i * 16 + q * 4;
#pragma unroll
            for (int rr = 0; rr < 4; rr++) {
                const int row = row0 + rr;
                float v = acc[i][j][rr];
                if (EPI == EPI_SCORES) {
                    ((float*)Cout)[(size_t)z * (size_t)sCz + (size_t)row * ldc + col] = v * alpha;
                } else if (EPI == EPI_GELU) {
                    v += bv;
                    float g = 0.5f * v * (1.0f + erff(v * 0.7071067811865475f));
                    ((USH*)Cout)[(size_t)row * ldc + col] = f2bf(g);
                } else if (EPI == EPI_GATE) {
                    v += bv;
                    float gate = 1.0f / (1.0f + expf(-v));
                    float o = gate * fmul[(size_t)row * ldc + col];
                    ((USH*)Cout)[(size_t)row * ldc + col] = f2bf(o);
                } else {
                    ((USH*)Cout)[(size_t)row * ldc + col] = f2bf(v + bv);
                }
            }
        }
    }
}

// ---------------------------------------------------------------
// means: z<24 -> y[z][d] = mean_n feats[z,n,d]; z==24 -> tg[d] = mean_t text
// z==25 -> init cell state (c=0, sigmoid(c)=0.5)
// ---------------------------------------------------------------
__global__ __launch_bounds__(256)
void means_k(const float* __restrict__ text, const float* __restrict__ feats,
             float* __restrict__ tg, float* __restrict__ yv, float* __restrict__ cst,
             float* __restrict__ scs)
{
    const int d = blockIdx.x * 256 + threadIdx.x;
    const int z = blockIdx.y;
    if (z < 24) {
        const float* f = feats + (size_t)z * 576 * 4096 + d;
        float s = 0.f;
        for (int n = 0; n < 576; n++) s += f[(size_t)n * 4096];
        yv[z * 4096 + d] = s * (1.0f / 576.0f);
    } else if (z == 24) {
        float s = 0.f;
        for (int t = 0; t < 128; t++) s += text[(size_t)t * 4096 + d];
        tg[d] = s * (1.0f / 128.0f);
    } else {
        cst[d] = 0.f;
        scs[d] = 0.5f;
    }
}

// ---------------------------------------------------------------
// f32 -> bf16 bulk convert
// ---------------------------------------------------------------
__global__ __launch_bounds__(256)
void f32_to_bf16(const float* __restrict__ src, USH* __restrict__ dst)
{
    const size_t base = ((size_t)blockIdx.x * 256 + threadIdx.x) * 8;
    float4 f0 = *reinterpret_cast<const float4*>(src + base);
    float4 f1 = *reinterpret_cast<const float4*>(src + base + 4);
    uint4 ov;
    ov.x = pack2bf(f0.x, f0.y); ov.y = pack2bf(f0.z, f0.w);
    ov.z = pack2bf(f1.x, f1.y); ov.w = pack2bf(f1.z, f1.w);
    *reinterpret_cast<uint4*>(dst + base) = ov;
}

// ---------------------------------------------------------------
// bf16 transpose: dst[d][s] = src[s][d]; src 13824 x 4096
// ---------------------------------------------------------------
__global__ __launch_bounds__(256)
void transpose_bf16(const USH* __restrict__ src, USH* __restrict__ dst)
{
    __shared__ USH T[64][72];
    const int s0 = blockIdx.x * 64;   // 216
    const int d0 = blockIdx.y * 64;   // 64
    const int tid = threadIdx.x;
    const int rr = tid >> 3;          // 0..31
    const int c8 = (tid & 7) * 8;     // 0..56
#pragma unroll
    for (int i = 0; i < 2; i++) {
        const int row = rr + i * 32;
        uint4 v = *reinterpret_cast<const uint4*>(src + (size_t)(s0 + row) * 4096 + d0 + c8);
        *reinterpret_cast<uint4*>(&T[row][c8]) = v;
    }
    __syncthreads();
#pragma unroll
    for (int i = 0; i < 2; i++) {
        const int drow = rr + i * 32;
        USH tmp[8];
#pragma unroll
        for (int j = 0; j < 8; j++) tmp[j] = T[c8 + j][drow];
        *reinterpret_cast<uint4*>(dst + (size_t)(d0 + drow) * 13824 + s0 + c8) =
            *reinterpret_cast<const uint4*>(tmp);
    }
}

// ---------------------------------------------------------------
// PV split-K reduce: att[t][h*512+d] = bf16( sum_kc part[h*8+kc][t][d] )
// ---------------------------------------------------------------
__global__ __launch_bounds__(256)
void pv_reduce(const float* __restrict__ part, USH* __restrict__ att)
{
    const int idx = blockIdx.x * 256 + threadIdx.x;
    const size_t o = (size_t)idx * 4;
    const int t = (int)(o >> 12);
    const int col = (int)(o & 4095);
    const int h = col >> 9;
    const int d = col & 511;
    const float* p = part + (size_t)h * 8 * 65536 + t * 512 + d;
    float4 s = {0.f, 0.f, 0.f, 0.f};
#pragma unroll
    for (int kc = 0; kc < 8; kc++) {
        float4 v = *reinterpret_cast<const float4*>(p + (size_t)kc * 65536);
        s.x += v.x; s.y += v.y; s.z += v.z; s.w += v.w;
    }
    uint2 ov;
    ov.x = pack2bf(s.x, s.y);
    ov.y = pack2bf(s.z, s.w);
    *reinterpret_cast<uint2*>(att + o) = ov;
}

// ---------------------------------------------------------------
// DSU precompute: pre[l,r] = W1[r,4096:8192].y_l + W1[r,8192:12288].tg + W1_b[r]
// ---------------------------------------------------------------
__global__ __launch_bounds__(256)
void dsu_pre(const float* __restrict__ W1w, const float* __restrict__ W1b,
             const float* __restrict__ yv, const float* __restrict__ tg,
             float* __restrict__ pre)
{
    const int rrow = blockIdx.x;
    const float* w = W1w + (size_t)rrow * 12288;
    const int tid = threadIdx.x;
    float wy[16];
    float at = 0.f;
#pragma unroll
    for (int i = 0; i < 16; i++) {
        const int k = tid + i * 256;
        wy[i] = w[4096 + k];
        at += w[8192 + k] * tg[k];
    }
#pragma unroll
    for (int o = 32; o > 0; o >>= 1) at += __shfl_down(at, o, 64);
    __shared__ float red[4];
    __shared__ float tgs;
    if ((tid & 63) == 0) red[tid >> 6] = at;
    __syncthreads();
    if (tid == 0) tgs = red[0] + red[1] + red[2] + red[3] + W1b[rrow];
    for (int l = 0; l < 24; l++) {
        const float* y = yv + (size_t)l * 4096;
        float a = 0.f;
#pragma unroll
        for (int i = 0; i < 16; i++) a += wy[i] * y[tid + i * 256];
#pragma unroll
        for (int o = 32; o > 0; o >>= 1) a += __shfl_down(a, o, 64);
        __syncthreads();
        if ((tid & 63) == 0) red[tid >> 6] = a;
        __syncthreads();
        if (tid == 0) pre[l * 1024 + rrow] = red[0] + red[1] + red[2] + red[3] + tgs;
    }
}

// ---------------------------------------------------------------
// DSU step 1: s[r] = relu(W1[r,0:4096].sig(c) + pre[l,r])
// ---------------------------------------------------------------
__global__ __launch_bounds__(256)
void dsu_s1(const float* __restrict__ W1w, const float* __restrict__ scs,
            const float* __restrict__ pre_l, float* __restrict__ sv)
{
    const int rrow = blockIdx.x;
    const float* w = W1w + (size_t)rrow * 12288;
    const int tid = threadIdx.x;
    float acc = 0.f;
#pragma unroll
    for (int i = 0; i < 16; i++) {
        const int k = tid + i * 256;
        acc += w[k] * scs[k];
    }
#pragma unroll
    for (int o = 32; o > 0; o >>= 1) acc += __shfl_down(acc, o, 64);
    __shared__ float red[4];
    if ((tid & 63) == 0) red[tid >> 6] = acc;
    __syncthreads();
    if (tid == 0) {
        float t = red[0] + red[1] + red[2] + red[3] + pre_l[rrow];
        sv[rrow] = fmaxf(t, 0.f);
    }
}

// ---------------------------------------------------------------
// DSU step 2: gates + cell update + ctx write + cached sigmoid(c)
// ---------------------------------------------------------------
__global__ __launch_bounds__(256)
void dsu_s2(const float* __restrict__ Wc, const float* __restrict__ Wcb,
            const float* __restrict__ Wi, const float* __restrict__ Wib,
            const float* __restrict__ Wf, const float* __restrict__ Wfb,
            const float* __restrict__ bc, const float* __restrict__ bi,
            const float* __restrict__ bfv,
             const float* __restrict__ sv, float* __restrict__ c,
             float* __restrict__ ctx_l, float* __restrict__ scs)
{
    const int d = blockIdx.x;
    const int tid = threadIdx.x;
    float a0 = 0.f, a1 = 0.f, a2 = 0.f;
    for (int k = tid; k < 1024; k += 256) {
        float s = sv[k];
        a0 += Wc[(size_t)d * 1024 + k] * s;
        a1 += Wi[(size_t)d * 1024 + k] * s;
        a2 += Wf[(size_t)d * 1024 + k] * s;
    }
#pragma unroll
    for (int o = 32; o > 0; o >>= 1) {
        a0 += __shfl_down(a0, o, 64);
        a1 += __shfl_down(a1, o, 64);
        a2 += __shfl_down(a2, o, 64);
    }
    __shared__ float red[3][4];
    if ((tid & 63) == 0) {
        red[0][tid >> 6] = a0; red[1][tid >> 6] = a1; red[2][tid >> 6] = a2;
    }
    __syncthreads();
    if (tid == 0) {
        float A0 = red[0][0] + red[0][1] + red[0][2] + red[0][3];
        float A1 = red[1][0] + red[1][1] + red[1][2] + red[1][3];
        float A2 = red[2][0] + red[2][1] + red[2][2] + red[2][3];
        float ct = tanhf(A0 + Wcb[d] + bc[d]);
        float ig = sigmoidf_(A1 + Wib[d] + bi[d]);
        float fg = sigmoidf_(A2 + Wfb[d] + bfv[d]);
        float cn = fg * c[d] + ig * ct;
        c[d] = cn;
        ctx_l[d] = cn;
        scs[d] = sigmoidf_(cn);
    }
}

// ---------------------------------------------------------------
// X = bf16( feats + ctx[layer] )
// ---------------------------------------------------------------
__global__ __launch_bounds__(256)
void make_x(const float* __restrict__ feats, const float* __restrict__ ctx,
            USH* __restrict__ X)
{
    const size_t base = ((size_t)blockIdx.x * 256 + threadIdx.x) * 8;
    const int row = (int)(base >> 12);
    const int l = row / 576;
    const float* cr = ctx + (size_t)l * 4096 + (base & 4095);
    float4 f0 = *reinterpret_cast<const float4*>(feats + base);
    float4 f1 = *reinterpret_cast<const float4*>(feats + base + 4);
    uint4 ov;
    ov.x = pack2bf(f0.x + cr[0], f0.y + cr[1]);
    ov.y = pack2bf(f0.z + cr[2], f0.w + cr[3]);
    ov.z = pack2bf(f1.x + cr[4], f1.y + cr[5]);
    ov.w = pack2bf(f1.z + cr[6], f1.w + cr[7]);
    *reinterpret_cast<uint4*>(X + base) = ov;
}

// ---------------------------------------------------------------
// LayerNorm over rows of width 4096
// ---------------------------------------------------------------
template <bool OUTF32>
__global__ __launch_bounds__(256)
void ln_rows(const USH* __restrict__ in, void* __restrict__ out,
             const float* __restrict__ g, const float* __restrict__ b)
{
    const int row = blockIdx.x;
    const USH* x = in + (size_t)row * 4096;
    const int tid = threadIdx.x;
    float vals[16];
    float s = 0.f, ss = 0.f;
#pragma unroll
    for (int i = 0; i < 16; i++) {
        float v = bf2f(x[tid + i * 256]);
        vals[i] = v; s += v; ss += v * v;
    }
#pragma unroll
    for (int off = 32; off > 0; off >>= 1) {
        s += __shfl_down(s, off, 64);
        ss += __shfl_down(ss, off, 64);
    }
    __shared__ float rs[4], rss[4];
    __shared__ float stats[2];
    if ((tid & 63) == 0) { rs[tid >> 6] = s; rss[tid >> 6] = ss; }
    __syncthreads();
    if (tid == 0) {
        float S = rs[0] + rs[1] + rs[2] + rs[3];
        float SS = rss[0] + rss[1] + rss[2] + rss[3];
        float mean = S * (1.0f / 4096.0f);
        float var = SS * (1.0f / 4096.0f) - mean * mean;
        stats[0] = mean;
        stats[1] = rsqrtf(var + 1e-5f);
    }
    __syncthreads();
    const float mean = stats[0], rstd = stats[1];
#pragma unroll
    for (int i = 0; i < 16; i++) {
        const int cidx = tid + i * 256;
        float v = (vals[i] - mean) * rstd * g[cidx] + b[cidx];
        if (OUTF32) ((float*)out)[(size_t)row * 4096 + cidx] = v;
        else ((USH*)out)[(size_t)row * 4096 + cidx] = f2bf(v);
    }
}

// ---------------------------------------------------------------
// softmax over 13824 per row (scores fp32 -> probs bf16)
// ---------------------------------------------------------------
__global__ __launch_bounds__(256)
void softmax_rows(const float* __restrict__ scores, USH* __restrict__ probs)
{
    const int row = blockIdx.x;   // h*128 + t
    const float* x = scores + (size_t)row * 13824;
    USH* p = probs + (size_t)row * 13824;
    const int tid = threadIdx.x;
    float mx = -1e30f;
    for (int i = tid; i < 13824; i += 256) mx = fmaxf(mx, x[i]);
#pragma unroll
    for (int off = 32; off > 0; off >>= 1) mx = fmaxf(mx, __shfl_down(mx, off, 64));
    __shared__ float rm[4];
    __shared__ float bm, bs;
    if ((tid & 63) == 0) rm[tid >> 6] = mx;
    __syncthreads();
    if (tid == 0) bm = fmaxf(fmaxf(rm[0], rm[1]), fmaxf(rm[2], rm[3]));
    __syncthreads();
    const float M = bm;
    float sum = 0.f;
    for (int i = tid; i < 13824; i += 256) sum += expf(x[i] - M);
#pragma unroll
    for (int off = 32; off > 0; off >>= 1) sum += __shfl_down(sum, off, 64);
    if ((tid & 63) == 0) rm[tid >> 6] = sum;
    __syncthreads();
    if (tid == 0) bs = 1.0f / (rm[0] + rm[1] + rm[2] + rm[3]);
    __syncthreads();
    const float inv = bs;
    for (int i = tid; i < 13824; i += 256) p[i] = f2bf(expf(x[i] - M) * inv);
}

// ---------------------------------------------------------------
extern "C" void kernel_launch(void* const* d_in, const int* in_sizes, int n_in,
                              void* d_out, int out_size, void* d_ws, size_t ws_size,
                              hipStream_t stream)
{
    const float* text = (const float*)d_in[0];
    const float* feats = (const float*)d_in[1];
    const float* W1w = (const float*)d_in[2];
    const float* W1b = (const float*)d_in[3];
    const float* Wcw = (const float*)d_in[4];
    const float* Wcb = (const float*)d_in[5];
    const float* Wiw = (const float*)d_in[6];
    const float* Wib = (const float*)d_in[7];
    const float* Wfw = (const float*)d_in[8];
    const float* Wfb = (const float*)d_in[9];
    const float* bc  = (const float*)d_in[10];
    const float* bi  = (const float*)d_in[11];
    const float* bfv = (const float*)d_in[12];
    const float* g1w = (const float*)d_in[13];
    const float* g1b = (const float*)d_in[14];
    const float* g2w = (const float*)d_in[15];
    const float* g2b = (const float*)d_in[16];
    const float* Wqw = (const float*)d_in[17];
    const float* Wqb = (const float*)d_in[18];
    const float* Wkw = (const float*)d_in[19];
    const float* Wkb = (const float*)d_in[20];
    const float* Wow = (const float*)d_in[21];
    const float* Wob = (const float*)d_in[22];
    const float* qng = (const float*)d_in[23];
    const float* qnb = (const float*)d_in[24];
    const float* kng = (const float*)d_in[25];
    const float* knb = (const float*)d_in[26];
    const float* ong = (const float*)d_in[27];
    const float* onb = (const float*)d_in[28];

    // ---- workspace layout (bump allocator, 256B aligned) ----
    char* base = (char*)d_ws;
    size_t off = 0;
    auto take = [&](size_t nbytes) -> char* {
        char* p = base + off;
        off += (nbytes + 255) & ~(size_t)255;
        return p;
    };
    const size_t BIG = (size_t)13824 * 4096 * 2;   // 113,246,208 B
    USH* P1 = (USH*)take(BIG);          // X -> K (LN in place) -> V^T
    USH* P2 = (USH*)take(BIG);          // H1; later: scores fp32 + probs bf16
    USH* P3 = (USH*)take(BIG);          // refreshed (V)
    float* tg  = (float*)take(4096 * 4);
    float* yv  = (float*)take(24 * 4096 * 4);
    float* cst = (float*)take(4096 * 4);
    float* scs = (float*)take(4096 * 4);
    float* sv  = (float*)take(1024 * 4);
    float* pre = (float*)take(24 * 1024 * 4);
    float* ctx = (float*)take(24 * 4096 * 4);
    USH* textb = (USH*)take((size_t)128 * 4096 * 2);
    USH* Qb   = (USH*)take((size_t)128 * 4096 * 2);
    USH* attb = (USH*)take((size_t)128 * 4096 * 2);
    USH* opre = (USH*)take((size_t)128 * 4096 * 2);
    USH* wb   = (USH*)take((size_t)4096 * 4096 * 2);   // bf16 weights; later PV fp32 partials
    float* scores = (float*)P2;                                   // 56,623,104 B
    USH* probs = (USH*)((char*)P2 + (size_t)8 * 128 * 13824 * 4); // + 28,311,552 B
    USH* vT = P1;                        // V^T overlay after K is consumed
    float* pvpart = (float*)wb;          // 64*128*512*4 = 16.8 MB (fits in wb)
    (void)ws_size; (void)in_sizes; (void)n_in; (void)out_size;

    // ---- 1. means + cell init + text->bf16 + recurrence-independent W1 part ----
    means_k<<<dim3(16, 26), 256, 0, stream>>>(text, feats, tg, yv, cst, scs);
    f32_to_bf16<<<256, 256, 0, stream>>>(text, textb);
    dsu_pre<<<1024, 256, 0, stream>>>(W1w, W1b, yv, tg, pre);

    // ---- 2. DSU recurrence (sequential over 24 layers) ----
    for (int l = 0; l < 24; l++) {
        dsu_s1<<<1024, 256, 0, stream>>>(W1w, scs, pre + (size_t)l * 1024, sv);
        dsu_s2<<<4096, 256, 0, stream>>>(Wcw, Wcb, Wiw, Wib, Wfw, Wfb, bc, bi, bfv,
                                         sv, cst, ctx + (size_t)l * 4096, scs);
    }

    // ---- 3. spatial gate (bf16 weights, 256^2 8-wave GEMM) ----
    make_x<<<27648, 256, 0, stream>>>(feats, ctx, P1);
    f32_to_bf16<<<8192, 256, 0, stream>>>(g1w, wb);
    gemm256<EPI_GELU><<<864, 512, 0, stream>>>(P1, wb, P2, g1b, nullptr, 4096);
    f32_to_bf16<<<8192, 256, 0, stream>>>(g2w, wb);
    gemm256<EPI_GATE><<<864, 512, 0, stream>>>(P2, wb, P3, g2b, feats, 4096);

    // ---- 4. K = LN(refreshed @ Wk^T + b) ----
    f32_to_bf16<<<8192, 256, 0, stream>>>(Wkw, wb);
    gemm256<EPI_PLAIN><<<864, 512, 0, stream>>>(P3, wb, P1, Wkb, nullptr, 4096);
    ln_rows<false><<<13824, 256, 0, stream>>>(P1, P1, kng, knb);

    // ---- 5. Q = LN(text @ Wq^T + b)  (tiny, fp32-W reg staging) ----
    gemm_bt<EPI_PLAIN, true><<<dim3(32, 1, 1), 256, 0, stream>>>(
        textb, 4096, 0, 0, 1, Wqw, 4096, 0, 0, Qb, 4096, 0, Wqb, nullptr, 1.f, 4096);
    ln_rows<false><<<128, 256, 0, stream>>>(Qb, Qb, qng, qnb);

    // ---- 6. scores = Q K^T / sqrt(512*24), per head ----
    const float alpha = 0.00902109753f;  // 1/sqrt(512*24)
    gemm_bt<EPI_SCORES, false><<<dim3(108, 1, 8), 256, 0, stream>>>(
        Qb, 4096, 512, 0, 1, P1, 4096, 512, 0, scores, 13824, (long long)128 * 13824,
        nullptr, nullptr, alpha, 512);

    // ---- 7. V^T, softmax, PV via split-K MFMA ----
    transpose_bf16<<<dim3(216, 64), 256, 0, stream>>>(P3, vT);
    softmax_rows<<<1024, 256, 0, stream>>>(scores, probs);
    gemm_bt<EPI_SCORES, false><<<dim3(4, 1, 64), 256, 0, stream>>>(
        probs, 13824, (long long)128 * 13824, 1728, 8,
        vT, 13824, (long long)512 * 13824, 1728,
        pvpart, 512, 65536,
        nullptr, nullptr, 1.0f, 1728);
    pv_reduce<<<512, 256, 0, stream>>>(pvpart, attb);

    // ---- 8. out = LN(att @ Wo^T + b), fp32 out ----
    gemm_bt<EPI_PLAIN, true><<<dim3(32, 1, 1), 256, 0, stream>>>(
        attb, 4096, 0, 0, 1, Wow, 4096, 0, 0, opre, 4096, 0, Wob, nullptr, 1.f, 4096);
    ln_rows<true><<<128, 256, 0, stream>>>(opre, (float*)d_out, ong, onb);
}